// Round 1
// baseline (671.357 us; speedup 1.0000x reference)
//
#include <hip/hip_runtime.h>

#define V 32000
#define H 256
#define S 2048
#define B 128
#define NC 64   // score/ctx chunks per b
#define CS 32   // s-rows per chunk

// K1: u[b,t] = sum_k h[b,k] * We[k,t],  We[k,t] = attn_W[k*2H + H + t]
__global__ __launch_bounds__(256) void k_u(const float* __restrict__ hid,
                                           const float* __restrict__ attn_W,
                                           float* __restrict__ u) {
    __shared__ float hl[H];
    int b = blockIdx.x, t = threadIdx.x;
    hl[t] = hid[b * H + t];
    __syncthreads();
    float acc = 0.f;
    for (int k = 0; k < H; ++k)
        acc += hl[k] * attn_W[k * (2 * H) + H + t];
    u[b * H + t] = acc;
}

// K2: per (b, chunk): scores, chunk-softmax stats, partial context. enc read ONCE.
__global__ __launch_bounds__(256) void k_scores(const float* __restrict__ enc,
                                                const float* __restrict__ u,
                                                float* __restrict__ scores,
                                                float* __restrict__ part_m,
                                                float* __restrict__ part_l,
                                                float* __restrict__ ctx_part) {
    __shared__ float encl[CS * H];
    __shared__ float ul[H];
    __shared__ float sl[CS];
    __shared__ float wx[CS];
    int b = blockIdx.x, c = blockIdx.y, t = threadIdx.x;
    ul[t] = u[b * H + t];
    int s0 = c * CS;
    // stage enc tile, coalesced float4 loads
    for (int i = t; i < CS * (H / 4); i += 256) {
        int row = i >> 6;          // H/4 = 64 vec4 per row
        int col = (i & 63) << 2;
        float4 f = *(const float4*)(enc + ((size_t)(s0 + row) * B + b) * H + col);
        *(float4*)(encl + row * H + col) = f;
    }
    __syncthreads();
    int w = t >> 6, l = t & 63;
    // each wave: 8 score rows
    for (int j = 0; j < 8; ++j) {
        int s = w * 8 + j;
        float4 e = *(const float4*)(encl + s * H + l * 4);
        float4 uu = *(const float4*)(ul + l * 4);
        float v = e.x * uu.x + e.y * uu.y + e.z * uu.z + e.w * uu.w;
        for (int off = 32; off; off >>= 1) v += __shfl_xor(v, off, 64);
        if (l == 0) {
            sl[s] = v;
            scores[(size_t)b * S + s0 + s] = v;
        }
    }
    __syncthreads();
    if (t < CS) {
        float m = sl[t];
        for (int off = 16; off; off >>= 1) m = fmaxf(m, __shfl_xor(m, off, 64));
        m = __shfl(m, 0, 64);  // broadcast (partners stay in lanes 0..31)
        float e = __expf(sl[t] - m);
        wx[t] = e;
        float lsum = e;
        for (int off = 16; off; off >>= 1) lsum += __shfl_xor(lsum, off, 64);
        if (t == 0) {
            int pc = b * NC + c;
            part_m[pc] = m;
            part_l[pc] = lsum;
        }
    }
    __syncthreads();
    float acc = 0.f;
    for (int s = 0; s < CS; ++s) acc += wx[s] * encl[s * H + t];
    ctx_part[((size_t)(b * NC + c)) * H + t] = acc;
}

// K3: combine chunk partials -> context (into x2 upper half) + attn_weights out
__global__ __launch_bounds__(256) void k_combine(const float* __restrict__ part_m,
                                                 const float* __restrict__ part_l,
                                                 const float* __restrict__ ctx_part,
                                                 const float* __restrict__ scores,
                                                 float* __restrict__ x2,
                                                 float* __restrict__ out_attn) {
    __shared__ float wf[NC];
    __shared__ float Ms, Ls;
    int b = blockIdx.x, t = threadIdx.x;
    if (t < NC) {
        float m = part_m[b * NC + t];
        float M = m;
        for (int off = 32; off; off >>= 1) M = fmaxf(M, __shfl_xor(M, off, 64));
        M = __shfl(M, 0, 64);
        float e = __expf(m - M);
        wf[t] = e;
        float lw = e * part_l[b * NC + t];
        for (int off = 32; off; off >>= 1) lw += __shfl_xor(lw, off, 64);
        if (t == 0) { Ms = M; Ls = lw; }
    }
    __syncthreads();
    float M = Ms, invL = 1.0f / Ls;
    float acc = 0.f;
    for (int c = 0; c < NC; ++c)
        acc += wf[c] * ctx_part[((size_t)(b * NC + c)) * H + t];
    x2[b * (2 * H) + H + t] = acc * invL;   // context (normalized!)
    for (int s = t; s < S; s += 256) {
        out_attn[(size_t)b * S + s] = __expf(scores[(size_t)b * S + s] - M) * invL;
    }
}

// K4: GRU cell. Block = one b, 768 threads = 12 waves.
// Each wave row-reduces 64 rows of W_ih and W_hh with lane-coalesced float4 loads.
__global__ __launch_bounds__(768) void k_gru(const int* __restrict__ ids,
                                             const float* __restrict__ hid,
                                             const float* __restrict__ emb,
                                             const float* __restrict__ W_ih,
                                             const float* __restrict__ W_hh,
                                             const float* __restrict__ b_ih,
                                             const float* __restrict__ b_hh,
                                             float* __restrict__ x2,
                                             float* __restrict__ out_h) {
    __shared__ float xl[2 * H];
    __shared__ float hl[H];
    __shared__ float gis[3 * H];
    __shared__ float ghs[3 * H];
    int b = blockIdx.x, t = threadIdx.x;
    if (t < H) xl[t] = emb[(size_t)ids[b] * H + t];
    else if (t < 2 * H) xl[t] = x2[b * (2 * H) + t];   // context half
    else hl[t - 2 * H] = hid[b * H + (t - 2 * H)];
    __syncthreads();
    int w = t >> 6, l = t & 63;
    float4 xa = *(const float4*)(xl + 4 * l);
    float4 xb = *(const float4*)(xl + H + 4 * l);
    float4 ha = *(const float4*)(hl + 4 * l);
    for (int jj = 0; jj < 64; ++jj) {
        int j = w * 64 + jj;
        const float* wr = W_ih + (size_t)j * (2 * H);
        float4 w1 = *(const float4*)(wr + 4 * l);
        float4 w2 = *(const float4*)(wr + H + 4 * l);
        float vi = w1.x * xa.x + w1.y * xa.y + w1.z * xa.z + w1.w * xa.w
                 + w2.x * xb.x + w2.y * xb.y + w2.z * xb.z + w2.w * xb.w;
        const float* vr = W_hh + (size_t)j * H;
        float4 w3 = *(const float4*)(vr + 4 * l);
        float vh = w3.x * ha.x + w3.y * ha.y + w3.z * ha.z + w3.w * ha.w;
        for (int off = 32; off; off >>= 1) {
            vi += __shfl_xor(vi, off, 64);
            vh += __shfl_xor(vh, off, 64);
        }
        if (l == 0) {
            gis[j] = vi + b_ih[j];
            ghs[j] = vh + b_hh[j];
        }
    }
    __syncthreads();
    if (t < H) {
        float r = 1.f / (1.f + __expf(-(gis[t] + ghs[t])));
        float z = 1.f / (1.f + __expf(-(gis[H + t] + ghs[H + t])));
        float n = tanhf(gis[2 * H + t] + r * ghs[2 * H + t]);
        float hn = (1.f - z) * n + z * hl[t];
        out_h[b * H + t] = hn;
        x2[b * (2 * H) + t] = hn;
    }
}

// K5: logits[b, v] = x2[b,:] . out_W[:, v] + out_b[v]  + FUSED per-(b,vtile)
// logsumexp partials (max + sum-exp) while acc is still in registers.
// thread: 4 v's x BT b's; block: 1024 v x 16 b; grid (32 v-tiles, 8 b-tiles)
//   = 256 blocks = 1/CU. BT=16 halves out_W logical traffic vs BT=8 (0.52 GB
//   through L2/L3 instead of 1.05 GB) -- the old grid oversubscribed the 4 MB
//   per-XCD L2 (4 concurrent 2 MB slices/XCD).
// NOTE: 32*1024 = 32768 > V=32000 -> tail guard REQUIRED. Tail is waves 1..3
// of block x=31 exactly (boundary 4t=256 at t=64), so the guard is wave-uniform.
// Inactive threads contribute -1e30/0 to the reductions and still hit barriers.
#define BT 16
#define NVC 32   // number of v-tile chunks for logsumexp partials
__global__ __launch_bounds__(256) void k_logits(const float* __restrict__ x2,
                                                const float* __restrict__ out_W,
                                                const float* __restrict__ out_b,
                                                float* __restrict__ logits,
                                                float* __restrict__ pm,
                                                float* __restrict__ pl) {
    __shared__ float wred[4][BT];
    __shared__ float Ms[BT];
    int t = threadIdx.x;
    int v0 = blockIdx.x * 1024 + 4 * t;
    int b0 = blockIdx.y * BT;
    bool act = v0 < V;
    float acc[BT][4];
    if (act) {
        float4 ob = *(const float4*)(out_b + v0);
#pragma unroll
        for (int bb = 0; bb < BT; ++bb) {
            acc[bb][0] = ob.x; acc[bb][1] = ob.y; acc[bb][2] = ob.z; acc[bb][3] = ob.w;
        }
        // one-k-step-ahead prefetch of the 4 W rows to cover L2 latency
        // (grid is 1 block/CU => 1 wave/SIMD, so ILP must come from the loop body)
        float4 cw[4];
#pragma unroll
        for (int ku = 0; ku < 4; ++ku)
            cw[ku] = *(const float4*)(out_W + (size_t)ku * V + v0);
        for (int k = 0; k < 2 * H; k += 4) {
            int kn = (k + 4 < 2 * H) ? (k + 4) : k;   // last iter: redundant reload
            float4 nw[4];
#pragma unroll
            for (int ku = 0; ku < 4; ++ku)
                nw[ku] = *(const float4*)(out_W + (size_t)(kn + ku) * V + v0);
#pragma unroll
            for (int bb = 0; bb < BT; ++bb) {
                // wave-uniform address -> s_load_dwordx4 through scalar cache
                float4 xv = *(const float4*)(x2 + ((b0 + bb) << 9) + k);
                acc[bb][0] += xv.x * cw[0].x + xv.y * cw[1].x + xv.z * cw[2].x + xv.w * cw[3].x;
                acc[bb][1] += xv.x * cw[0].y + xv.y * cw[1].y + xv.z * cw[2].y + xv.w * cw[3].y;
                acc[bb][2] += xv.x * cw[0].z + xv.y * cw[1].z + xv.z * cw[2].z + xv.w * cw[3].z;
                acc[bb][3] += xv.x * cw[0].w + xv.y * cw[1].w + xv.z * cw[2].w + xv.w * cw[3].w;
            }
#pragma unroll
            for (int ku = 0; ku < 4; ++ku) cw[ku] = nw[ku];
        }
#pragma unroll
        for (int bb = 0; bb < BT; ++bb) {
            float4 r = make_float4(acc[bb][0], acc[bb][1], acc[bb][2], acc[bb][3]);
            *(float4*)(logits + (size_t)(b0 + bb) * V + v0) = r;
        }
    } else {
#pragma unroll
        for (int bb = 0; bb < BT; ++bb)
            acc[bb][0] = acc[bb][1] = acc[bb][2] = acc[bb][3] = -1e30f;
    }
    // ---- fused per-(b, v-tile) logsumexp partials ----
    int wid = t >> 6, l = t & 63;
#pragma unroll
    for (int bb = 0; bb < BT; ++bb) {
        float m = fmaxf(fmaxf(acc[bb][0], acc[bb][1]), fmaxf(acc[bb][2], acc[bb][3]));
        for (int off = 32; off; off >>= 1) m = fmaxf(m, __shfl_xor(m, off, 64));
        if (l == 0) wred[wid][bb] = m;
    }
    __syncthreads();
    if (t < BT)
        Ms[t] = fmaxf(fmaxf(wred[0][t], wred[1][t]), fmaxf(wred[2][t], wred[3][t]));
    __syncthreads();
#pragma unroll
    for (int bb = 0; bb < BT; ++bb) {
        float M = Ms[bb];
        float sacc = 0.f;
        if (act) {
            sacc = __expf(acc[bb][0] - M) + __expf(acc[bb][1] - M)
                 + __expf(acc[bb][2] - M) + __expf(acc[bb][3] - M);
        }
        for (int off = 32; off; off >>= 1) sacc += __shfl_xor(sacc, off, 64);
        if (l == 0) wred[wid][bb] = sacc;
    }
    __syncthreads();
    if (t < BT) {
        float L = wred[0][t] + wred[1][t] + wred[2][t] + wred[3][t];
        pm[(b0 + t) * NVC + blockIdx.x] = Ms[t];
        pl[(b0 + t) * NVC + blockIdx.x] = L;
    }
}

// K6b: combine NVC partials per row -> M_b, log L_b
__global__ __launch_bounds__(128) void k_lsm_comb(const float* __restrict__ pm,
                                                  const float* __restrict__ pl,
                                                  float* __restrict__ Ml,
                                                  float* __restrict__ Ll) {
    int b = threadIdx.x;
    float M = -1e30f;
    for (int c = 0; c < NVC; ++c) M = fmaxf(M, pm[b * NVC + c]);
    float L = 0.f;
    for (int c = 0; c < NVC; ++c) L += pl[b * NVC + c] * __expf(pm[b * NVC + c] - M);
    Ml[b] = M;
    Ll[b] = logf(L);
}

// K6c: out[b,v] = logit - M_b - logL_b  (same tail guard as k_logits!)
__global__ __launch_bounds__(256) void k_lsm_write(const float* __restrict__ logits,
                                                   const float* __restrict__ Ml,
                                                   const float* __restrict__ Ll,
                                                   float* __restrict__ out) {
    int b = blockIdx.y, t = threadIdx.x;
    int v = blockIdx.x * 1024 + 4 * t;
    if (v >= V) return;
    float off = Ml[b] + Ll[b];
    float4 x = *(const float4*)(logits + (size_t)b * V + v);
    float4 o = make_float4(x.x - off, x.y - off, x.z - off, x.w - off);
    *(float4*)(out + (size_t)b * V + v) = o;
}

extern "C" void kernel_launch(void* const* d_in, const int* in_sizes, int n_in,
                              void* d_out, int out_size, void* d_ws, size_t ws_size,
                              hipStream_t stream) {
    const int* ids = (const int*)d_in[0];
    const float* hid = (const float*)d_in[1];
    const float* enc = (const float*)d_in[2];
    const float* emb = (const float*)d_in[3];
    const float* attn_W = (const float*)d_in[4];
    // d_in[5] attn_b: unused (per-row constant shift, softmax-invariant)
    const float* W_ih = (const float*)d_in[6];
    const float* W_hh = (const float*)d_in[7];
    const float* b_ih = (const float*)d_in[8];
    const float* b_hh = (const float*)d_in[9];
    const float* out_W = (const float*)d_in[10];
    const float* out_b = (const float*)d_in[11];

    float* out = (float*)d_out;
    float* out_logprob = out;                        // B*V
    float* out_h = out + (size_t)B * V;              // B*H
    float* out_attn = out + (size_t)B * V + B * H;   // B*S

    float* w = (float*)d_ws;
    float* u        = w;                    // 32768
    float* scores   = w + 32768;            // 262144
    float* part_m   = w + 294912;           // 8192
    float* part_l   = w + 303104;           // 8192
    float* ctx_part = w + 311296;           // 2097152
    float* x2       = w + 2408448;          // 65536
    float* logits   = w + 2473984;          // 4096000
    float* lsm      = w + 6569984;          // B*NVC = 4096
    float* lsl      = w + 6574080;          // 4096
    float* Ml       = w + 6578176;          // 128
    float* Ll       = w + 6578304;          // 128

    hipLaunchKernelGGL(k_u, dim3(B), dim3(256), 0, stream, hid, attn_W, u);
    hipLaunchKernelGGL(k_scores, dim3(B, NC), dim3(256), 0, stream,
                       enc, u, scores, part_m, part_l, ctx_part);
    hipLaunchKernelGGL(k_combine, dim3(B), dim3(256), 0, stream,
                       part_m, part_l, ctx_part, scores, x2, out_attn);
    hipLaunchKernelGGL(k_gru, dim3(B), dim3(768), 0, stream,
                       ids, hid, emb, W_ih, W_hh, b_ih, b_hh, x2, out_h);
    hipLaunchKernelGGL(k_logits, dim3(32, B / BT), dim3(256), 0, stream,
                       x2, out_W, out_b, logits, lsm, lsl);
    hipLaunchKernelGGL(k_lsm_comb, dim3(1), dim3(128), 0, stream, lsm, lsl, Ml, Ll);
    hipLaunchKernelGGL(k_lsm_write, dim3(32, B), dim3(256), 0, stream,
                       logits, Ml, Ll, out_logprob);
}

// Round 2
// 650.528 us; speedup vs baseline: 1.0320x; 1.0320x over previous
//
#include <hip/hip_runtime.h>

#define V 32000
#define H 256
#define S 2048
#define B 128
#define NC 64   // score/ctx chunks per b
#define CS 32   // s-rows per chunk

// K1: u[b,t] = sum_k h[b,k] * We[k,t],  We[k,t] = attn_W[k*2H + H + t]
__global__ __launch_bounds__(256) void k_u(const float* __restrict__ hid,
                                           const float* __restrict__ attn_W,
                                           float* __restrict__ u) {
    __shared__ float hl[H];
    int b = blockIdx.x, t = threadIdx.x;
    hl[t] = hid[b * H + t];
    __syncthreads();
    float acc = 0.f;
    for (int k = 0; k < H; ++k)
        acc += hl[k] * attn_W[k * (2 * H) + H + t];
    u[b * H + t] = acc;
}

// K2: per (b, chunk): scores, chunk-softmax stats, partial context. enc read ONCE.
__global__ __launch_bounds__(256) void k_scores(const float* __restrict__ enc,
                                                const float* __restrict__ u,
                                                float* __restrict__ scores,
                                                float* __restrict__ part_m,
                                                float* __restrict__ part_l,
                                                float* __restrict__ ctx_part) {
    __shared__ float encl[CS * H];
    __shared__ float ul[H];
    __shared__ float sl[CS];
    __shared__ float wx[CS];
    int b = blockIdx.x, c = blockIdx.y, t = threadIdx.x;
    ul[t] = u[b * H + t];
    int s0 = c * CS;
    // stage enc tile, coalesced float4 loads
    for (int i = t; i < CS * (H / 4); i += 256) {
        int row = i >> 6;          // H/4 = 64 vec4 per row
        int col = (i & 63) << 2;
        float4 f = *(const float4*)(enc + ((size_t)(s0 + row) * B + b) * H + col);
        *(float4*)(encl + row * H + col) = f;
    }
    __syncthreads();
    int w = t >> 6, l = t & 63;
    // each wave: 8 score rows
    for (int j = 0; j < 8; ++j) {
        int s = w * 8 + j;
        float4 e = *(const float4*)(encl + s * H + l * 4);
        float4 uu = *(const float4*)(ul + l * 4);
        float v = e.x * uu.x + e.y * uu.y + e.z * uu.z + e.w * uu.w;
        for (int off = 32; off; off >>= 1) v += __shfl_xor(v, off, 64);
        if (l == 0) {
            sl[s] = v;
            scores[(size_t)b * S + s0 + s] = v;
        }
    }
    __syncthreads();
    if (t < CS) {
        float m = sl[t];
        for (int off = 16; off; off >>= 1) m = fmaxf(m, __shfl_xor(m, off, 64));
        m = __shfl(m, 0, 64);  // broadcast (partners stay in lanes 0..31)
        float e = __expf(sl[t] - m);
        wx[t] = e;
        float lsum = e;
        for (int off = 16; off; off >>= 1) lsum += __shfl_xor(lsum, off, 64);
        if (t == 0) {
            int pc = b * NC + c;
            part_m[pc] = m;
            part_l[pc] = lsum;
        }
    }
    __syncthreads();
    float acc = 0.f;
    for (int s = 0; s < CS; ++s) acc += wx[s] * encl[s * H + t];
    ctx_part[((size_t)(b * NC + c)) * H + t] = acc;
}

// K3: combine chunk partials -> context (into x2 upper half) + attn_weights out
__global__ __launch_bounds__(256) void k_combine(const float* __restrict__ part_m,
                                                 const float* __restrict__ part_l,
                                                 const float* __restrict__ ctx_part,
                                                 const float* __restrict__ scores,
                                                 float* __restrict__ x2,
                                                 float* __restrict__ out_attn) {
    __shared__ float wf[NC];
    __shared__ float Ms, Ls;
    int b = blockIdx.x, t = threadIdx.x;
    if (t < NC) {
        float m = part_m[b * NC + t];
        float M = m;
        for (int off = 32; off; off >>= 1) M = fmaxf(M, __shfl_xor(M, off, 64));
        M = __shfl(M, 0, 64);
        float e = __expf(m - M);
        wf[t] = e;
        float lw = e * part_l[b * NC + t];
        for (int off = 32; off; off >>= 1) lw += __shfl_xor(lw, off, 64);
        if (t == 0) { Ms = M; Ls = lw; }
    }
    __syncthreads();
    float M = Ms, invL = 1.0f / Ls;
    float acc = 0.f;
    for (int c = 0; c < NC; ++c)
        acc += wf[c] * ctx_part[((size_t)(b * NC + c)) * H + t];
    x2[b * (2 * H) + H + t] = acc * invL;   // context (normalized!)
    for (int s = t; s < S; s += 256) {
        out_attn[(size_t)b * S + s] = __expf(scores[(size_t)b * S + s] - M) * invL;
    }
}

// K4: GRU cell. Block = one b, 768 threads = 12 waves.
__global__ __launch_bounds__(768) void k_gru(const int* __restrict__ ids,
                                             const float* __restrict__ hid,
                                             const float* __restrict__ emb,
                                             const float* __restrict__ W_ih,
                                             const float* __restrict__ W_hh,
                                             const float* __restrict__ b_ih,
                                             const float* __restrict__ b_hh,
                                             float* __restrict__ x2,
                                             float* __restrict__ out_h) {
    __shared__ float xl[2 * H];
    __shared__ float hl[H];
    __shared__ float gis[3 * H];
    __shared__ float ghs[3 * H];
    int b = blockIdx.x, t = threadIdx.x;
    if (t < H) xl[t] = emb[(size_t)ids[b] * H + t];
    else if (t < 2 * H) xl[t] = x2[b * (2 * H) + t];   // context half
    else hl[t - 2 * H] = hid[b * H + (t - 2 * H)];
    __syncthreads();
    int w = t >> 6, l = t & 63;
    float4 xa = *(const float4*)(xl + 4 * l);
    float4 xb = *(const float4*)(xl + H + 4 * l);
    float4 ha = *(const float4*)(hl + 4 * l);
    for (int jj = 0; jj < 64; ++jj) {
        int j = w * 64 + jj;
        const float* wr = W_ih + (size_t)j * (2 * H);
        float4 w1 = *(const float4*)(wr + 4 * l);
        float4 w2 = *(const float4*)(wr + H + 4 * l);
        float vi = w1.x * xa.x + w1.y * xa.y + w1.z * xa.z + w1.w * xa.w
                 + w2.x * xb.x + w2.y * xb.y + w2.z * xb.z + w2.w * xb.w;
        const float* vr = W_hh + (size_t)j * H;
        float4 w3 = *(const float4*)(vr + 4 * l);
        float vh = w3.x * ha.x + w3.y * ha.y + w3.z * ha.z + w3.w * ha.w;
        for (int off = 32; off; off >>= 1) {
            vi += __shfl_xor(vi, off, 64);
            vh += __shfl_xor(vh, off, 64);
        }
        if (l == 0) {
            gis[j] = vi + b_ih[j];
            ghs[j] = vh + b_hh[j];
        }
    }
    __syncthreads();
    if (t < H) {
        float r = 1.f / (1.f + __expf(-(gis[t] + ghs[t])));
        float z = 1.f / (1.f + __expf(-(gis[H + t] + ghs[H + t])));
        float n = tanhf(gis[2 * H + t] + r * ghs[2 * H + t]);
        float hn = (1.f - z) * n + z * hl[t];
        out_h[b * H + t] = hn;
        x2[b * (2 * H) + t] = hn;
    }
}

// K5: logits GEMM, k-split. ph[kh][b][v] = sum_{k in half kh} x2[b,k]*W[k,v]
//   (+ out_b for kh==0).
// Grid (32 v-tiles, 4 b-tiles, 2 k-halves) = 256 blocks = 1/CU.
// Thread: 4 v x 32 b -> acc[32][4] = 128 VGPR. __launch_bounds__(256,1) frees
// the allocator (R1 bug: BT=16 + fused-LSE tail spilled acc, VGPR_Count=48,
// 174us latency-bound). x2 tile staged in LDS (32 KB) -> uniform-address
// ds_read broadcast, no SGPR pressure. W double-buffered one k-step ahead.
// out_W logical traffic = 4 b-tile replications x 65.5 MB = 262 MB (L3).
// NOTE: 32*1024 = 32768 > V=32000 -> tail guard REQUIRED (after the staging
// loop + barrier; no barriers follow).
#define BT2 32
#define KH 256
__global__ __launch_bounds__(256, 1) void k_logits(const float* __restrict__ x2,
                                                   const float* __restrict__ out_W,
                                                   const float* __restrict__ out_b,
                                                   float* __restrict__ ph) {
    __shared__ float xs[BT2 * KH];
    int t = threadIdx.x;
    int v0 = blockIdx.x * 1024 + 4 * t;
    int b0 = blockIdx.y * BT2;
    int kh = blockIdx.z;
    int k0 = kh * KH;
    // stage x2[b0..b0+31][k0..k0+255] into LDS, coalesced
    for (int i = t; i < BT2 * (KH / 4); i += 256) {
        int bb = i >> 6;               // KH/4 = 64 vec4 per row
        int kk = (i & 63) << 2;
        *(float4*)(xs + bb * KH + kk) =
            *(const float4*)(x2 + (size_t)(b0 + bb) * (2 * H) + k0 + kk);
    }
    __syncthreads();
    if (v0 >= V) return;   // tail: waves 1..3 of block x=31 (wave-uniform)

    float acc[BT2][4];
    if (kh == 0) {
        float4 ob = *(const float4*)(out_b + v0);
#pragma unroll
        for (int bb = 0; bb < BT2; ++bb) {
            acc[bb][0] = ob.x; acc[bb][1] = ob.y; acc[bb][2] = ob.z; acc[bb][3] = ob.w;
        }
    } else {
#pragma unroll
        for (int bb = 0; bb < BT2; ++bb)
            acc[bb][0] = acc[bb][1] = acc[bb][2] = acc[bb][3] = 0.f;
    }

    const float* Wp = out_W + (size_t)k0 * V + v0;
    float4 cw[4];
#pragma unroll
    for (int ku = 0; ku < 4; ++ku)
        cw[ku] = *(const float4*)(Wp + (size_t)ku * V);
    for (int k = 0; k < KH; k += 4) {
        int kn = (k + 4 < KH) ? (k + 4) : k;   // last iter: redundant reload
        float4 nw[4];
#pragma unroll
        for (int ku = 0; ku < 4; ++ku)
            nw[ku] = *(const float4*)(Wp + (size_t)(kn + ku) * V);
#pragma unroll
        for (int bb = 0; bb < BT2; ++bb) {
            float4 xv = *(const float4*)(xs + bb * KH + k);  // uniform addr -> broadcast
            acc[bb][0] += xv.x * cw[0].x + xv.y * cw[1].x + xv.z * cw[2].x + xv.w * cw[3].x;
            acc[bb][1] += xv.x * cw[0].y + xv.y * cw[1].y + xv.z * cw[2].y + xv.w * cw[3].y;
            acc[bb][2] += xv.x * cw[0].z + xv.y * cw[1].z + xv.z * cw[2].z + xv.w * cw[3].z;
            acc[bb][3] += xv.x * cw[0].w + xv.y * cw[1].w + xv.z * cw[2].w + xv.w * cw[3].w;
        }
#pragma unroll
        for (int ku = 0; ku < 4; ++ku) cw[ku] = nw[ku];
    }

    float* dst = ph + (size_t)kh * B * V;
#pragma unroll
    for (int bb = 0; bb < BT2; ++bb) {
        float4 r = make_float4(acc[bb][0], acc[bb][1], acc[bb][2], acc[bb][3]);
        *(float4*)(dst + (size_t)(b0 + bb) * V + v0) = r;
    }
}

// K6a: per (chunk of 4000 v, b): z = ph0+ph1, partial max / sumexp.
// Two passes; second pass re-reads the 32 KB chunk from L2.
__global__ __launch_bounds__(256) void k_lsm_part(const float* __restrict__ ph,
                                                  float* __restrict__ pm,
                                                  float* __restrict__ pl) {
    __shared__ float wm[4];
    __shared__ float wsum[4];
    int c = blockIdx.x, b = blockIdx.y, t = threadIdx.x;
    const float* r0 = ph + (size_t)b * V + c * 4000;
    const float* r1 = ph + (size_t)(B + b) * V + c * 4000;
    float m = -1e30f;
    for (int i = 4 * t; i < 4000; i += 1024) {
        float4 a = *(const float4*)(r0 + i);
        float4 q = *(const float4*)(r1 + i);
        m = fmaxf(m, fmaxf(fmaxf(a.x + q.x, a.y + q.y), fmaxf(a.z + q.z, a.w + q.w)));
    }
    for (int off = 32; off; off >>= 1) m = fmaxf(m, __shfl_xor(m, off, 64));
    if ((t & 63) == 0) wm[t >> 6] = m;
    __syncthreads();
    float M = fmaxf(fmaxf(wm[0], wm[1]), fmaxf(wm[2], wm[3]));
    float sacc = 0.f;
    for (int i = 4 * t; i < 4000; i += 1024) {
        float4 a = *(const float4*)(r0 + i);
        float4 q = *(const float4*)(r1 + i);
        sacc += __expf(a.x + q.x - M) + __expf(a.y + q.y - M)
              + __expf(a.z + q.z - M) + __expf(a.w + q.w - M);
    }
    for (int off = 32; off; off >>= 1) sacc += __shfl_xor(sacc, off, 64);
    if ((t & 63) == 0) wsum[t >> 6] = sacc;
    __syncthreads();
    if (t == 0) {
        pm[b * 8 + c] = M;
        pl[b * 8 + c] = wsum[0] + wsum[1] + wsum[2] + wsum[3];
    }
}

// K6b: combine 8 partials per row -> M_b, log L_b
__global__ __launch_bounds__(128) void k_lsm_comb(const float* __restrict__ pm,
                                                  const float* __restrict__ pl,
                                                  float* __restrict__ Ml,
                                                  float* __restrict__ Ll) {
    int b = threadIdx.x;
    float M = -1e30f;
    for (int c = 0; c < 8; ++c) M = fmaxf(M, pm[b * 8 + c]);
    float L = 0.f;
    for (int c = 0; c < 8; ++c) L += pl[b * 8 + c] * __expf(pm[b * 8 + c] - M);
    Ml[b] = M;
    Ll[b] = logf(L);
}

// K6c: out[b,v] = (ph0+ph1) - M_b - logL_b  (same tail guard as k_logits!)
__global__ __launch_bounds__(256) void k_lsm_write(const float* __restrict__ ph,
                                                   const float* __restrict__ Ml,
                                                   const float* __restrict__ Ll,
                                                   float* __restrict__ out) {
    int b = blockIdx.y, t = threadIdx.x;
    int v = blockIdx.x * 1024 + 4 * t;
    if (v >= V) return;
    float off = Ml[b] + Ll[b];
    float4 a = *(const float4*)(ph + (size_t)b * V + v);
    float4 q = *(const float4*)(ph + (size_t)(B + b) * V + v);
    float4 o = make_float4(a.x + q.x - off, a.y + q.y - off,
                           a.z + q.z - off, a.w + q.w - off);
    *(float4*)(out + (size_t)b * V + v) = o;
}

extern "C" void kernel_launch(void* const* d_in, const int* in_sizes, int n_in,
                              void* d_out, int out_size, void* d_ws, size_t ws_size,
                              hipStream_t stream) {
    const int* ids = (const int*)d_in[0];
    const float* hid = (const float*)d_in[1];
    const float* enc = (const float*)d_in[2];
    const float* emb = (const float*)d_in[3];
    const float* attn_W = (const float*)d_in[4];
    // d_in[5] attn_b: unused (per-row constant shift, softmax-invariant)
    const float* W_ih = (const float*)d_in[6];
    const float* W_hh = (const float*)d_in[7];
    const float* b_ih = (const float*)d_in[8];
    const float* b_hh = (const float*)d_in[9];
    const float* out_W = (const float*)d_in[10];
    const float* out_b = (const float*)d_in[11];

    float* out = (float*)d_out;
    float* out_logprob = out;                        // B*V
    float* out_h = out + (size_t)B * V;              // B*H
    float* out_attn = out + (size_t)B * V + B * H;   // B*S

    float* w = (float*)d_ws;
    float* u        = w;                    // 32768
    float* scores   = w + 32768;            // 262144
    float* part_m   = w + 294912;           // 8192
    float* part_l   = w + 303104;           // 8192
    float* ctx_part = w + 311296;           // 2097152
    float* x2       = w + 2408448;          // 65536
    float* ph       = w + 2473984;          // 2*B*V = 8192000
    float* lsm      = w + 10665984;         // 1024
    float* lsl      = w + 10667008;         // 1024
    float* Ml       = w + 10668032;         // 128
    float* Ll       = w + 10668160;         // 128

    hipLaunchKernelGGL(k_u, dim3(B), dim3(256), 0, stream, hid, attn_W, u);
    hipLaunchKernelGGL(k_scores, dim3(B, NC), dim3(256), 0, stream,
                       enc, u, scores, part_m, part_l, ctx_part);
    hipLaunchKernelGGL(k_combine, dim3(B), dim3(256), 0, stream,
                       part_m, part_l, ctx_part, scores, x2, out_attn);
    hipLaunchKernelGGL(k_gru, dim3(B), dim3(768), 0, stream,
                       ids, hid, emb, W_ih, W_hh, b_ih, b_hh, x2, out_h);
    hipLaunchKernelGGL(k_logits, dim3(32, B / BT2, 2), dim3(256), 0, stream,
                       x2, out_W, out_b, ph);
    hipLaunchKernelGGL(k_lsm_part, dim3(8, B), dim3(256), 0, stream, ph, lsm, lsl);
    hipLaunchKernelGGL(k_lsm_comb, dim3(1), dim3(128), 0, stream, lsm, lsl, Ml, Ll);
    hipLaunchKernelGGL(k_lsm_write, dim3(32, B), dim3(256), 0, stream,
                       ph, Ml, Ll, out_logprob);
}

// Round 4
// 584.108 us; speedup vs baseline: 1.1494x; 1.1137x over previous
//
#include <hip/hip_runtime.h>

#define V 32000
#define H 256
#define S 2048
#define B 128
#define NC 64   // score/ctx chunks per b
#define CS 32   // s-rows per chunk

// K1: u[b,t] = sum_k h[b,k] * We[k,t],  We[k,t] = attn_W[k*2H + H + t]
__global__ __launch_bounds__(256) void k_u(const float* __restrict__ hid,
                                           const float* __restrict__ attn_W,
                                           float* __restrict__ u) {
    __shared__ float hl[H];
    int b = blockIdx.x, t = threadIdx.x;
    hl[t] = hid[b * H + t];
    __syncthreads();
    float acc = 0.f;
    for (int k = 0; k < H; ++k)
        acc += hl[k] * attn_W[k * (2 * H) + H + t];
    u[b * H + t] = acc;
}

// K2: per (b, chunk): scores, chunk-softmax stats, partial context. enc read ONCE.
__global__ __launch_bounds__(256) void k_scores(const float* __restrict__ enc,
                                                const float* __restrict__ u,
                                                float* __restrict__ scores,
                                                float* __restrict__ part_m,
                                                float* __restrict__ part_l,
                                                float* __restrict__ ctx_part) {
    __shared__ float encl[CS * H];
    __shared__ float ul[H];
    __shared__ float sl[CS];
    __shared__ float wx[CS];
    int b = blockIdx.x, c = blockIdx.y, t = threadIdx.x;
    ul[t] = u[b * H + t];
    int s0 = c * CS;
    // stage enc tile, coalesced float4 loads
    for (int i = t; i < CS * (H / 4); i += 256) {
        int row = i >> 6;          // H/4 = 64 vec4 per row
        int col = (i & 63) << 2;
        float4 f = *(const float4*)(enc + ((size_t)(s0 + row) * B + b) * H + col);
        *(float4*)(encl + row * H + col) = f;
    }
    __syncthreads();
    int w = t >> 6, l = t & 63;
    // each wave: 8 score rows
    for (int j = 0; j < 8; ++j) {
        int s = w * 8 + j;
        float4 e = *(const float4*)(encl + s * H + l * 4);
        float4 uu = *(const float4*)(ul + l * 4);
        float v = e.x * uu.x + e.y * uu.y + e.z * uu.z + e.w * uu.w;
        for (int off = 32; off; off >>= 1) v += __shfl_xor(v, off, 64);
        if (l == 0) {
            sl[s] = v;
            scores[(size_t)b * S + s0 + s] = v;
        }
    }
    __syncthreads();
    if (t < CS) {
        float m = sl[t];
        for (int off = 16; off; off >>= 1) m = fmaxf(m, __shfl_xor(m, off, 64));
        m = __shfl(m, 0, 64);  // broadcast (partners stay in lanes 0..31)
        float e = __expf(sl[t] - m);
        wx[t] = e;
        float lsum = e;
        for (int off = 16; off; off >>= 1) lsum += __shfl_xor(lsum, off, 64);
        if (t == 0) {
            int pc = b * NC + c;
            part_m[pc] = m;
            part_l[pc] = lsum;
        }
    }
    __syncthreads();
    float acc = 0.f;
    for (int s = 0; s < CS; ++s) acc += wx[s] * encl[s * H + t];
    ctx_part[((size_t)(b * NC + c)) * H + t] = acc;
}

// K3: combine chunk partials -> context (into x2 upper half) + attn_weights out
__global__ __launch_bounds__(256) void k_combine(const float* __restrict__ part_m,
                                                 const float* __restrict__ part_l,
                                                 const float* __restrict__ ctx_part,
                                                 const float* __restrict__ scores,
                                                 float* __restrict__ x2,
                                                 float* __restrict__ out_attn) {
    __shared__ float wf[NC];
    __shared__ float Ms, Ls;
    int b = blockIdx.x, t = threadIdx.x;
    if (t < NC) {
        float m = part_m[b * NC + t];
        float M = m;
        for (int off = 32; off; off >>= 1) M = fmaxf(M, __shfl_xor(M, off, 64));
        M = __shfl(M, 0, 64);
        float e = __expf(m - M);
        wf[t] = e;
        float lw = e * part_l[b * NC + t];
        for (int off = 32; off; off >>= 1) lw += __shfl_xor(lw, off, 64);
        if (t == 0) { Ms = M; Ls = lw; }
    }
    __syncthreads();
    float M = Ms, invL = 1.0f / Ls;
    float acc = 0.f;
    for (int c = 0; c < NC; ++c)
        acc += wf[c] * ctx_part[((size_t)(b * NC + c)) * H + t];
    x2[b * (2 * H) + H + t] = acc * invL;   // context (normalized!)
    for (int s = t; s < S; s += 256) {
        out_attn[(size_t)b * S + s] = __expf(scores[(size_t)b * S + s] - M) * invL;
    }
}

// K4: GRU cell. Block = one b, 768 threads = 12 waves.
__global__ __launch_bounds__(768) void k_gru(const int* __restrict__ ids,
                                             const float* __restrict__ hid,
                                             const float* __restrict__ emb,
                                             const float* __restrict__ W_ih,
                                             const float* __restrict__ W_hh,
                                             const float* __restrict__ b_ih,
                                             const float* __restrict__ b_hh,
                                             float* __restrict__ x2,
                                             float* __restrict__ out_h) {
    __shared__ float xl[2 * H];
    __shared__ float hl[H];
    __shared__ float gis[3 * H];
    __shared__ float ghs[3 * H];
    int b = blockIdx.x, t = threadIdx.x;
    if (t < H) xl[t] = emb[(size_t)ids[b] * H + t];
    else if (t < 2 * H) xl[t] = x2[b * (2 * H) + t];   // context half
    else hl[t - 2 * H] = hid[b * H + (t - 2 * H)];
    __syncthreads();
    int w = t >> 6, l = t & 63;
    float4 xa = *(const float4*)(xl + 4 * l);
    float4 xb = *(const float4*)(xl + H + 4 * l);
    float4 ha = *(const float4*)(hl + 4 * l);
    for (int jj = 0; jj < 64; ++jj) {
        int j = w * 64 + jj;
        const float* wr = W_ih + (size_t)j * (2 * H);
        float4 w1 = *(const float4*)(wr + 4 * l);
        float4 w2 = *(const float4*)(wr + H + 4 * l);
        float vi = w1.x * xa.x + w1.y * xa.y + w1.z * xa.z + w1.w * xa.w
                 + w2.x * xb.x + w2.y * xb.y + w2.z * xb.z + w2.w * xb.w;
        const float* vr = W_hh + (size_t)j * H;
        float4 w3 = *(const float4*)(vr + 4 * l);
        float vh = w3.x * ha.x + w3.y * ha.y + w3.z * ha.z + w3.w * ha.w;
        for (int off = 32; off; off >>= 1) {
            vi += __shfl_xor(vi, off, 64);
            vh += __shfl_xor(vh, off, 64);
        }
        if (l == 0) {
            gis[j] = vi + b_ih[j];
            ghs[j] = vh + b_hh[j];
        }
    }
    __syncthreads();
    if (t < H) {
        float r = 1.f / (1.f + __expf(-(gis[t] + ghs[t])));
        float z = 1.f / (1.f + __expf(-(gis[H + t] + ghs[H + t])));
        float n = tanhf(gis[2 * H + t] + r * ghs[2 * H + t]);
        float hn = (1.f - z) * n + z * hl[t];
        out_h[b * H + t] = hn;
        x2[b * (2 * H) + t] = hn;
    }
}

// K5: logits GEMM, W-read-ONCE structure.
// ph[kh][b][v] = sum_{k in half kh} x2[b,k]*W[k,v]  (+ out_b for kh==0).
// Grid (125 v-tiles, 2 k-halves) = 250 blocks; block = 256 v-cols x ALL 128 b
// x 256 k. 125*256 = 32000 exactly -> NO TAIL. Each out_W column is read by
// exactly ONE block => zero L2/L3 replication (R0/R1/R2 all replicated W 4-16x
// and sat at ~150-174us, VALUBusy ~20%, latency-bound).
// 512 threads = 8 waves = 2 waves/SIMD. Thread = 4v x 16b -> acc[16][4] =
// 64 VGPR. x2 half-tile [128][256] = 128 KB LDS (gfx950 allows up to 160 KB);
// ds_reads are wave-uniform broadcasts (g = t>>6 wave-uniform, conflict-free).
// W wave-loads: 1 KB contiguous, coalesced; all 8 waves load the SAME 4 rows
// per k-step -> L1-absorbed 8-way reuse.
// R3 POST-MORTEM: previous version double-advanced the store pointer
// (dst + bb*V AND dst += V) -> OOB writes past the workspace -> GPU fault ->
// container crash. Store below advances dst by V exactly once per row.
#define VT 256
#define KHF 256
__global__ __launch_bounds__(512, 2) void k_logits(const float* __restrict__ x2,
                                                   const float* __restrict__ out_W,
                                                   const float* __restrict__ out_b,
                                                   float* __restrict__ ph) {
    __shared__ float xs[B * KHF];   // 128 KB
    int t = threadIdx.x;
    int kh = blockIdx.y;
    int k0 = kh * KHF;
    // stage x2[0..127][k0..k0+255] into LDS (x2 is L2-hot from k_gru)
    for (int i = t; i < B * (KHF / 4); i += 512) {
        int bb = i >> 6;               // 64 float4 per row
        int kk = (i & 63) << 2;
        *(float4*)(xs + bb * KHF + kk) =
            *(const float4*)(x2 + (size_t)bb * (2 * H) + k0 + kk);
    }
    __syncthreads();

    int q = t & 63;            // v-quad within tile (per-lane)
    int g = t >> 6;            // b-group 0..7 (wave-uniform)
    int v0 = blockIdx.x * VT + q * 4;

    float acc[16][4];
    if (kh == 0) {
        float4 ob = *(const float4*)(out_b + v0);
#pragma unroll
        for (int bb = 0; bb < 16; ++bb) {
            acc[bb][0] = ob.x; acc[bb][1] = ob.y; acc[bb][2] = ob.z; acc[bb][3] = ob.w;
        }
    } else {
#pragma unroll
        for (int bb = 0; bb < 16; ++bb)
            acc[bb][0] = acc[bb][1] = acc[bb][2] = acc[bb][3] = 0.f;
    }

    const float* Wp = out_W + (size_t)k0 * V + v0;
    const float* xrow0 = xs + (g * 16) * KHF;
    float4 cw[4];
#pragma unroll
    for (int ku = 0; ku < 4; ++ku)
        cw[ku] = *(const float4*)(Wp + (size_t)ku * V);
    for (int k = 0; k < KHF; k += 4) {
        int kn = (k + 4 < KHF) ? (k + 4) : k;   // last iter: redundant reload
        float4 nw[4];
#pragma unroll
        for (int ku = 0; ku < 4; ++ku)
            nw[ku] = *(const float4*)(Wp + (size_t)(kn + ku) * V);
#pragma unroll
        for (int bb = 0; bb < 16; ++bb) {
            float4 xv = *(const float4*)(xrow0 + bb * KHF + k);  // uniform -> broadcast
            acc[bb][0] += xv.x * cw[0].x + xv.y * cw[1].x + xv.z * cw[2].x + xv.w * cw[3].x;
            acc[bb][1] += xv.x * cw[0].y + xv.y * cw[1].y + xv.z * cw[2].y + xv.w * cw[3].y;
            acc[bb][2] += xv.x * cw[0].z + xv.y * cw[1].z + xv.z * cw[2].z + xv.w * cw[3].z;
            acc[bb][3] += xv.x * cw[0].w + xv.y * cw[1].w + xv.z * cw[2].w + xv.w * cw[3].w;
        }
#pragma unroll
        for (int ku = 0; ku < 4; ++ku) cw[ku] = nw[ku];
    }

    float* dst = ph + (size_t)kh * B * V + (size_t)(g * 16) * V + v0;
#pragma unroll
    for (int bb = 0; bb < 16; ++bb) {
        *(float4*)dst = make_float4(acc[bb][0], acc[bb][1], acc[bb][2], acc[bb][3]);
        dst += V;   // exactly one advance per b-row (R3 bug: was double-advanced)
    }
}

// K6a: per (chunk of 4000 v, b): z = ph0+ph1, partial max / sumexp.
__global__ __launch_bounds__(256) void k_lsm_part(const float* __restrict__ ph,
                                                  float* __restrict__ pm,
                                                  float* __restrict__ pl) {
    __shared__ float wm[4];
    __shared__ float wsum[4];
    int c = blockIdx.x, b = blockIdx.y, t = threadIdx.x;
    const float* r0 = ph + (size_t)b * V + c * 4000;
    const float* r1 = ph + (size_t)(B + b) * V + c * 4000;
    float m = -1e30f;
    for (int i = 4 * t; i < 4000; i += 1024) {
        float4 a = *(const float4*)(r0 + i);
        float4 q = *(const float4*)(r1 + i);
        m = fmaxf(m, fmaxf(fmaxf(a.x + q.x, a.y + q.y), fmaxf(a.z + q.z, a.w + q.w)));
    }
    for (int off = 32; off; off >>= 1) m = fmaxf(m, __shfl_xor(m, off, 64));
    if ((t & 63) == 0) wm[t >> 6] = m;
    __syncthreads();
    float M = fmaxf(fmaxf(wm[0], wm[1]), fmaxf(wm[2], wm[3]));
    float sacc = 0.f;
    for (int i = 4 * t; i < 4000; i += 1024) {
        float4 a = *(const float4*)(r0 + i);
        float4 q = *(const float4*)(r1 + i);
        sacc += __expf(a.x + q.x - M) + __expf(a.y + q.y - M)
              + __expf(a.z + q.z - M) + __expf(a.w + q.w - M);
    }
    for (int off = 32; off; off >>= 1) sacc += __shfl_xor(sacc, off, 64);
    if ((t & 63) == 0) wsum[t >> 6] = sacc;
    __syncthreads();
    if (t == 0) {
        pm[b * 8 + c] = M;
        pl[b * 8 + c] = wsum[0] + wsum[1] + wsum[2] + wsum[3];
    }
}

// K6b: combine 8 partials per row -> M_b, log L_b
__global__ __launch_bounds__(128) void k_lsm_comb(const float* __restrict__ pm,
                                                  const float* __restrict__ pl,
                                                  float* __restrict__ Ml,
                                                  float* __restrict__ Ll) {
    int b = threadIdx.x;
    float M = -1e30f;
    for (int c = 0; c < 8; ++c) M = fmaxf(M, pm[b * 8 + c]);
    float L = 0.f;
    for (int c = 0; c < 8; ++c) L += pl[b * 8 + c] * __expf(pm[b * 8 + c] - M);
    Ml[b] = M;
    Ll[b] = logf(L);
}

// K6c: out[b,v] = (ph0+ph1) - M_b - logL_b  (tail guard: 32*1024 > V)
__global__ __launch_bounds__(256) void k_lsm_write(const float* __restrict__ ph,
                                                   const float* __restrict__ Ml,
                                                   const float* __restrict__ Ll,
                                                   float* __restrict__ out) {
    int b = blockIdx.y, t = threadIdx.x;
    int v = blockIdx.x * 1024 + 4 * t;
    if (v >= V) return;
    float off = Ml[b] + Ll[b];
    float4 a = *(const float4*)(ph + (size_t)b * V + v);
    float4 q = *(const float4*)(ph + (size_t)(B + b) * V + v);
    float4 o = make_float4(a.x + q.x - off, a.y + q.y - off,
                           a.z + q.z - off, a.w + q.w - off);
    *(float4*)(out + (size_t)b * V + v) = o;
}

extern "C" void kernel_launch(void* const* d_in, const int* in_sizes, int n_in,
                              void* d_out, int out_size, void* d_ws, size_t ws_size,
                              hipStream_t stream) {
    const int* ids = (const int*)d_in[0];
    const float* hid = (const float*)d_in[1];
    const float* enc = (const float*)d_in[2];
    const float* emb = (const float*)d_in[3];
    const float* attn_W = (const float*)d_in[4];
    // d_in[5] attn_b: unused (per-row constant shift, softmax-invariant)
    const float* W_ih = (const float*)d_in[6];
    const float* W_hh = (const float*)d_in[7];
    const float* b_ih = (const float*)d_in[8];
    const float* b_hh = (const float*)d_in[9];
    const float* out_W = (const float*)d_in[10];
    const float* out_b = (const float*)d_in[11];

    float* out = (float*)d_out;
    float* out_logprob = out;                        // B*V
    float* out_h = out + (size_t)B * V;              // B*H
    float* out_attn = out + (size_t)B * V + B * H;   // B*S

    float* w = (float*)d_ws;
    float* u        = w;                    // 32768
    float* scores   = w + 32768;            // 262144
    float* part_m   = w + 294912;           // 8192
    float* part_l   = w + 303104;           // 8192
    float* ctx_part = w + 311296;           // 2097152
    float* x2       = w + 2408448;          // 65536
    float* ph       = w + 2473984;          // 2*B*V = 8192000
    float* lsm      = w + 10665984;         // 1024
    float* lsl      = w + 10667008;         // 1024
    float* Ml       = w + 10668032;         // 128
    float* Ll       = w + 10668160;         // 128

    hipLaunchKernelGGL(k_u, dim3(B), dim3(256), 0, stream, hid, attn_W, u);
    hipLaunchKernelGGL(k_scores, dim3(B, NC), dim3(256), 0, stream,
                       enc, u, scores, part_m, part_l, ctx_part);
    hipLaunchKernelGGL(k_combine, dim3(B), dim3(256), 0, stream,
                       part_m, part_l, ctx_part, scores, x2, out_attn);
    hipLaunchKernelGGL(k_gru, dim3(B), dim3(768), 0, stream,
                       ids, hid, emb, W_ih, W_hh, b_ih, b_hh, x2, out_h);
    hipLaunchKernelGGL(k_logits, dim3(125, 2), dim3(512), 0, stream,
                       x2, out_W, out_b, ph);
    hipLaunchKernelGGL(k_lsm_part, dim3(8, B), dim3(256), 0, stream, ph, lsm, lsl);
    hipLaunchKernelGGL(k_lsm_comb, dim3(1), dim3(128), 0, stream, lsm, lsl, Ml, Ll);
    hipLaunchKernelGGL(k_lsm_write, dim3(32, B), dim3(256), 0, stream,
                       ph, Ml, Ll, out_logprob);
}